// Round 5
// baseline (322.236 us; speedup 1.0000x reference)
//
#include <hip/hip_runtime.h>

// Reference numpy/jnp math is UNFUSED IEEE f32 — disable FMA contraction so
// the catastrophically-cancelled det (compared against EPS=1e-7) and the
// 1/det-scaled shifts are bit-identical to the reference.
#pragma clang fp contract(off)

// Problem constants (from setup_inputs): B=2, C=4, D=6, H=512, W=512, f32.
constexpr int B_ = 2, C_ = 4, D_ = 6, H_ = 512, W_ = 512;
constexpr int HW_  = H_ * W_;        // 262144
constexpr int DHW_ = D_ * HW_;       // 1572864
constexpr int BC_  = B_ * C_;        // 8
constexpr int TOT_ = BC_ * DHW_;     // 12582912
constexpr int CAP_ = 32768;          // seed-list capacity (E[seeds]=12.6K, fixed input)

#define EPS_ 1e-7f
#define MAX_SHIFT_ 0.6f
#define BONUS_ 10.0f
#define N_ITERS_ 5

// ---------------------------------------------------------------------------
// 3x3x3 quadratic-fit Cramer solve; p points at the (interior) center voxel.
// Op ordering mirrors the reference exactly (f32, no contraction).
__device__ __forceinline__ void solve3(const float* __restrict__ p,
                                       float& sx, float& sy, float& ss,
                                       float& gds, bool& sol)
{
    #pragma clang fp contract(off)
    float c    = p[0];
    float xp   = p[1],          xm   = p[-1];
    float yp   = p[W_],         ym   = p[-W_];
    float spv  = p[HW_],        smv  = p[-HW_];
    float xpyp = p[W_ + 1],     xmyp = p[W_ - 1];
    float xpym = p[-W_ + 1],    xmym = p[-W_ - 1];
    float xpsp = p[HW_ + 1],    xmsp = p[HW_ - 1];
    float xpsm = p[-HW_ + 1],   xmsm = p[-HW_ - 1];
    float ypsp = p[HW_ + W_],   ymsp = p[HW_ - W_];
    float ypsm = p[-HW_ + W_],  ymsm = p[-HW_ - W_];

    float gx = 0.5f * (xp - xm);
    float gy = 0.5f * (yp - ym);
    float gs = 0.5f * (spv - smv);
    float dxx = xp - 2.0f * c + xm;
    float dyy = yp - 2.0f * c + ym;
    float dss = spv - 2.0f * c + smv;
    float dxy = 0.25f * (xpyp - xmyp - xpym + xmym);
    float dxs = 0.25f * (xpsp - xmsp - xpsm + xmsm);
    float dys = 0.25f * (ypsp - ymsp - ypsm + ymsm);

    float cf00 = dyy * dss - dys * dys;
    float cf01 = dxy * dss - dys * dxs;
    float cf02 = dxy * dys - dyy * dxs;
    float det  = dxx * cf00 - dxy * cf01 + dxs * cf02;
    sol = fabsf(det) > EPS_;
    float sd = sol ? det : 1.0f;
    float r0 = -gx, r1 = -gy, r2 = -gs;
    sx = (r0 * cf00 - dxy * (r1 * dss - dys * r2) + dxs * (r1 * dys - dyy * r2)) / sd;
    sy = (dxx * (r1 * dss - dys * r2) - r0 * cf01 + dxs * (dxy * r2 - r1 * dxs)) / sd;
    ss = (dxx * (dyy * r2 - r1 * dys) - dxy * (dxy * r2 - r1 * dxs) + r0 * cf02) / sd;
    gds = gx * sx + gy * sy + gs * ss;
}

// Reference walk with EXACT early termination:
//  - `valid` is monotone: once false, shifts are masked to 0 forever and the
//    final outputs are the defaults (+BONUS on y). Break.
//  - if valid and all steps are 0, the position is unchanged, so every later
//    iteration recomputes identical values. Break (result frozen). Bit-exact.
__device__ void walk_and_write(const float* __restrict__ x,
                               float* __restrict__ out, int idx)
{
    #pragma clang fp contract(off)
    int w  = idx & (W_ - 1);
    int h  = (idx >> 9) & (H_ - 1);
    int t  = idx >> 18;
    int d  = t % D_;
    int bc = t / D_;
    int sp = idx - bc * DHW_;
    const float* xb = x + bc * DHW_;
    float xc = x[idx];

    int dd = 0, dh = 0, dwo = 0;
    bool valid = true;
    float shx = 0.0f, shy = 0.0f, shs = 0.0f, gk = 0.0f;

    #pragma unroll 1
    for (int it = 0; it < N_ITERS_; ++it) {
        int di = min(max(d + dd, 1), D_ - 2);
        int hi = min(max(h + dh, 1), H_ - 2);
        int wi = min(max(w + dwo, 1), W_ - 2);
        const float* p = xb + di * HW_ + hi * W_ + wi;

        float sx, sy, ssv, gds; bool sol;
        solve3(p, sx, sy, ssv, gds, sol);

        valid = valid && sol;
        if (!valid) break;                 // defaults from here on — exact

        shx = sx; shy = sy; shs = ssv; gk = gds;   // vf == 1 on this path

        int stx = (shx > MAX_SHIFT_) ? 1 : ((shx < -MAX_SHIFT_) ? -1 : 0);
        int sty = (shy > MAX_SHIFT_) ? 1 : ((shy < -MAX_SHIFT_) ? -1 : 0);
        int sts = (shs > MAX_SHIFT_) ? 1 : ((shs < -MAX_SHIFT_) ? -1 : 0);
        dwo += stx;
        dh  += sty;
        dd  += sts;
        valid = (abs(dd) <= 1) && (abs(dh) <= 1) && (abs(dwo) <= 1);
        if (!valid) break;                 // radius breach — defaults, exact
        if ((stx | sty | sts) == 0) break; // fixed point — frozen, exact
    }

    if (valid) {
        int di = min(max(d + dd, 1), D_ - 2);
        int hi = min(max(h + dh, 1), H_ - 2);
        int wi = min(max(w + dwo, 1), W_ - 2);
        float cur = xb[di * HW_ + hi * W_ + wi];
        float refined = cur + 0.5f * gk;
        out[(bc * 3 + 0) * DHW_ + sp] = (float)(d + dd)  + shs;
        out[(bc * 3 + 1) * DHW_ + sp] = (float)(w + dwo) + shx;
        out[(bc * 3 + 2) * DHW_ + sp] = (float)(h + dh)  + shy;
        out[BC_ * 3 * DHW_ + idx]     = refined + BONUS_;
    } else {
        // coords defaults already written by the stream kernel
        out[BC_ * 3 * DHW_ + idx]     = xc + BONUS_;
    }
}

// ---------------------------------------------------------------------------
__global__ void zero_counter_kernel(unsigned int* __restrict__ counter)
{
    if (threadIdx.x == 0 && blockIdx.x == 0) counter[0] = 0u;
}

// Wave-aggregated seed append (all 64 lanes active when called).
__device__ __forceinline__ void append_seed(int pred, int idx, int lane,
                                            unsigned int* __restrict__ counter,
                                            int* __restrict__ list)
{
    unsigned long long bal = __ballot(pred != 0);
    if (bal != 0ULL) {                      // wave-uniform
        unsigned int base = 0;
        if (lane == 0) base = atomicAdd(counter, (unsigned)__popcll(bal));
        base = (unsigned)__shfl((int)base, 0, 64);
        if (pred) {
            unsigned int slot = base + (unsigned)__popcll(bal & ((1ULL << lane) - 1ULL));
            if (slot < (unsigned)CAP_) list[slot] = idx;
        }
    }
}

// Kernel A: pure streaming, 4 voxels/thread. Writes default outputs for ALL
// voxels and appends seed indices to the compacted list.
__global__ __launch_bounds__(256)
void stream_kernel(const float4* __restrict__ x4,
                   const int4*  __restrict__ m4,
                   float* __restrict__ out,
                   unsigned int* __restrict__ counter,
                   int* __restrict__ list)
{
    int tid  = blockIdx.x * 256 + threadIdx.x;   // 0 .. TOT/4-1
    int idx4 = tid << 2;

    int w  = idx4 & (W_ - 1);
    int h  = (idx4 >> 9) & (H_ - 1);
    int t  = idx4 >> 18;
    int d  = t % D_;
    int bc = t / D_;
    int sp = idx4 - bc * DHW_;

    float4 xv = x4[tid];
    int4   mv = m4[tid];

    // y_max default = x
    *(float4*)(out + BC_ * 3 * DHW_ + idx4) = xv;

    // coords defaults: cs=d, cx=w.., cy=h
    float fd = (float)d, fh = (float)h;
    float4 csv = {fd, fd, fd, fd};
    float4 cxv = {(float)w, (float)(w + 1), (float)(w + 2), (float)(w + 3)};
    float4 cyv = {fh, fh, fh, fh};
    float* ob = out + (bc * 3) * DHW_ + sp;
    *(float4*)(ob)            = csv;
    *(float4*)(ob + DHW_)     = cxv;
    *(float4*)(ob + 2 * DHW_) = cyv;

    int lane = threadIdx.x & 63;
    append_seed(mv.x, idx4 + 0, lane, counter, list);
    append_seed(mv.y, idx4 + 1, lane, counter, list);
    append_seed(mv.z, idx4 + 2, lane, counter, list);
    append_seed(mv.w, idx4 + 3, lane, counter, list);
}

// Kernel B: one thread per seed — walk-waves are dense (all lanes useful).
__global__ __launch_bounds__(256)
void sparse_kernel(const float* __restrict__ x,
                   float* __restrict__ out,
                   const unsigned int* __restrict__ counter,
                   const int* __restrict__ list)
{
    unsigned int n = counter[0];
    if (n > (unsigned)CAP_) n = CAP_;
    unsigned int tid = blockIdx.x * 256 + threadIdx.x;
    if (tid >= n) return;
    walk_and_write(x, out, list[tid]);
}

// ---------------------------------------------------------------------------
// Fallback single kernel (round-4 version + early break) if ws too small.
__global__ __launch_bounds__(256)
void fused_kernel(const float4* __restrict__ x4,
                  const int4*  __restrict__ m4,
                  float* __restrict__ out)
{
    int tid  = blockIdx.x * 256 + threadIdx.x;
    int idx4 = tid << 2;
    int w  = idx4 & (W_ - 1);
    int h  = (idx4 >> 9) & (H_ - 1);
    int t  = idx4 >> 18;
    int d  = t % D_;
    int bc = t / D_;
    int sp = idx4 - bc * DHW_;

    float4 xv = x4[tid];
    int4   mv = m4[tid];

    *(float4*)(out + BC_ * 3 * DHW_ + idx4) = xv;
    float fd = (float)d, fh = (float)h;
    float4 csv = {fd, fd, fd, fd};
    float4 cxv = {(float)w, (float)(w + 1), (float)(w + 2), (float)(w + 3)};
    float4 cyv = {fh, fh, fh, fh};
    float* ob = out + (bc * 3) * DHW_ + sp;
    *(float4*)(ob)            = csv;
    *(float4*)(ob + DHW_)     = cxv;
    *(float4*)(ob + 2 * DHW_) = cyv;

    bool any_lane = (mv.x | mv.y | mv.z | mv.w) != 0;
    if (__ballot(any_lane) == 0ULL) return;

    const float* x = (const float*)x4;
    if (mv.x != 0) walk_and_write(x, out, idx4 + 0);
    if (mv.y != 0) walk_and_write(x, out, idx4 + 1);
    if (mv.z != 0) walk_and_write(x, out, idx4 + 2);
    if (mv.w != 0) walk_and_write(x, out, idx4 + 3);
}

extern "C" void kernel_launch(void* const* d_in, const int* in_sizes, int n_in,
                              void* d_out, int out_size, void* d_ws, size_t ws_size,
                              hipStream_t stream) {
    const float* x    = (const float*)d_in[0];
    const int*   mask = (const int*)d_in[1];
    float*       out  = (float*)d_out;

    size_t need = 256 + (size_t)CAP_ * sizeof(int);
    if (ws_size >= need) {
        unsigned int* counter = (unsigned int*)d_ws;
        int*          list    = (int*)((char*)d_ws + 256);

        zero_counter_kernel<<<1, 64, 0, stream>>>(counter);
        int blocksA = (TOT_ / 4) / 256;              // 12288
        stream_kernel<<<blocksA, 256, 0, stream>>>(
            (const float4*)x, (const int4*)mask, out, counter, list);
        int blocksB = CAP_ / 256;                    // 128
        sparse_kernel<<<blocksB, 256, 0, stream>>>(x, out, counter, list);
    } else {
        int blocks = (TOT_ / 4) / 256;
        fused_kernel<<<blocks, 256, 0, stream>>>(
            (const float4*)x, (const int4*)mask, out);
    }
}

// Round 6
// 264.680 us; speedup vs baseline: 1.2175x; 1.2175x over previous
//
#include <hip/hip_runtime.h>

// Reference numpy/jnp math is UNFUSED IEEE f32 — disable FMA contraction so
// the catastrophically-cancelled det (compared against EPS=1e-7) and the
// 1/det-scaled shifts are bit-identical to the reference.
#pragma clang fp contract(off)

// Problem constants (from setup_inputs): B=2, C=4, D=6, H=512, W=512, f32.
constexpr int B_ = 2, C_ = 4, D_ = 6, H_ = 512, W_ = 512;
constexpr int HW_  = H_ * W_;        // 262144
constexpr int DHW_ = D_ * HW_;       // 1572864
constexpr int BC_  = B_ * C_;        // 8
constexpr int TOT_ = BC_ * DHW_;     // 12582912

#define EPS_ 1e-7f
#define MAX_SHIFT_ 0.6f
#define BONUS_ 10.0f
#define N_ITERS_ 5

// ---------------------------------------------------------------------------
// 3x3x3 quadratic-fit Cramer solve; p points at the (interior) center voxel.
// Op ordering mirrors the reference exactly (f32, no contraction).
__device__ __forceinline__ void solve3(const float* __restrict__ p,
                                       float& sx, float& sy, float& ss,
                                       float& gds, bool& sol)
{
    #pragma clang fp contract(off)
    float c    = p[0];
    float xp   = p[1],          xm   = p[-1];
    float yp   = p[W_],         ym   = p[-W_];
    float spv  = p[HW_],        smv  = p[-HW_];
    float xpyp = p[W_ + 1],     xmyp = p[W_ - 1];
    float xpym = p[-W_ + 1],    xmym = p[-W_ - 1];
    float xpsp = p[HW_ + 1],    xmsp = p[HW_ - 1];
    float xpsm = p[-HW_ + 1],   xmsm = p[-HW_ - 1];
    float ypsp = p[HW_ + W_],   ymsp = p[HW_ - W_];
    float ypsm = p[-HW_ + W_],  ymsm = p[-HW_ - W_];

    float gx = 0.5f * (xp - xm);
    float gy = 0.5f * (yp - ym);
    float gs = 0.5f * (spv - smv);
    float dxx = xp - 2.0f * c + xm;
    float dyy = yp - 2.0f * c + ym;
    float dss = spv - 2.0f * c + smv;
    float dxy = 0.25f * (xpyp - xmyp - xpym + xmym);
    float dxs = 0.25f * (xpsp - xmsp - xpsm + xmsm);
    float dys = 0.25f * (ypsp - ymsp - ypsm + ymsm);

    float cf00 = dyy * dss - dys * dys;
    float cf01 = dxy * dss - dys * dxs;
    float cf02 = dxy * dys - dyy * dxs;
    float det  = dxx * cf00 - dxy * cf01 + dxs * cf02;
    sol = fabsf(det) > EPS_;
    float sd = sol ? det : 1.0f;
    float r0 = -gx, r1 = -gy, r2 = -gs;
    sx = (r0 * cf00 - dxy * (r1 * dss - dys * r2) + dxs * (r1 * dys - dyy * r2)) / sd;
    sy = (dxx * (r1 * dss - dys * r2) - r0 * cf01 + dxs * (dxy * r2 - r1 * dxs)) / sd;
    ss = (dxx * (dyy * r2 - r1 * dys) - dxy * (dxy * r2 - r1 * dxs) + r0 * cf02) / sd;
    gds = gx * sx + gy * sy + gs * ss;
}

// ---------------------------------------------------------------------------
// One fused pass, one thread per voxel (empirically the fastest structure:
// every extra kernel launch costs ~15-20us in this harness). Default coord
// outputs stream out first (nontemporal — no reuse, keep L2 for x); seed
// lanes then run the walk with EXACT early termination and overwrite.
__global__ __launch_bounds__(256)
void AdaptiveQuadInterp3d_kernel(const float* __restrict__ x,
                                 const int* __restrict__ mask,
                                 float* __restrict__ out)
{
    int idx = blockIdx.x * 256 + threadIdx.x;

    int w  = idx & (W_ - 1);
    int h  = (idx >> 9) & (H_ - 1);
    int t  = idx >> 18;          // bc*D + d   (HW = 2^18)
    int d  = t % D_;
    int bc = t / D_;
    int sp = idx - bc * DHW_;

    float xc = x[idx];
    int   m  = mask[idx];        // bool input materialized as int32

    // Default coords: cs=d, cx=w, cy=h. Streamed nontemporally; seed lanes
    // overwrite below (same thread, same address → program-order safe).
    float* cb = out + (bc * 3) * DHW_ + sp;
    __builtin_nontemporal_store((float)d, cb);
    __builtin_nontemporal_store((float)w, cb + DHW_);
    __builtin_nontemporal_store((float)h, cb + 2 * DHW_);

    float yv = xc;               // y_max default = x

    // Wave-uniform skip: 0.999^64 ≈ 94% of waves have no seeds.
    if (__ballot(m != 0) != 0ULL) {
        if (m != 0) {
            const float* xb = x + bc * DHW_;
            int dsd = 0, dsh = 0, dsw = 0;
            bool valid = true;
            float shx = 0.0f, shy = 0.0f, shs = 0.0f, gk = 0.0f;

            // Exact early termination:
            //  - `valid` is monotone: once false, shifts mask to 0 forever and
            //    outputs are the defaults (+BONUS on y). Break.
            //  - valid with all-zero steps = fixed point: later iterations
            //    recompute identical values. Break. Bit-exact vs reference.
            #pragma unroll 1
            for (int it = 0; it < N_ITERS_; ++it) {
                int di = min(max(d + dsd, 1), D_ - 2);
                int hi = min(max(h + dsh, 1), H_ - 2);
                int wi = min(max(w + dsw, 1), W_ - 2);
                const float* p = xb + di * HW_ + hi * W_ + wi;

                float sx, sy, ssv, gds; bool sol;
                solve3(p, sx, sy, ssv, gds, sol);

                if (!sol) { valid = false; break; }   // defaults — exact

                shx = sx; shy = sy; shs = ssv; gk = gds;

                int stx = (shx > MAX_SHIFT_) ? 1 : ((shx < -MAX_SHIFT_) ? -1 : 0);
                int sty = (shy > MAX_SHIFT_) ? 1 : ((shy < -MAX_SHIFT_) ? -1 : 0);
                int sts = (shs > MAX_SHIFT_) ? 1 : ((shs < -MAX_SHIFT_) ? -1 : 0);
                dsw += stx;
                dsh += sty;
                dsd += sts;
                valid = (abs(dsd) <= 1) && (abs(dsh) <= 1) && (abs(dsw) <= 1);
                if (!valid) break;                    // radius breach — exact
                if ((stx | sty | sts) == 0) break;    // fixed point — exact
            }

            if (valid) {
                int di = min(max(d + dsd, 1), D_ - 2);
                int hi = min(max(h + dsh, 1), H_ - 2);
                int wi = min(max(w + dsw, 1), W_ - 2);
                float cur = xb[di * HW_ + hi * W_ + wi];
                __builtin_nontemporal_store((float)(d + dsd) + shs, cb);
                __builtin_nontemporal_store((float)(w + dsw) + shx, cb + DHW_);
                __builtin_nontemporal_store((float)(h + dsh) + shy, cb + 2 * DHW_);
                yv = (cur + 0.5f * gk) + BONUS_;
            } else {
                yv = xc + BONUS_;   // coord defaults already stored
            }
        }
    }

    __builtin_nontemporal_store(yv, out + BC_ * 3 * DHW_ + idx);
}

extern "C" void kernel_launch(void* const* d_in, const int* in_sizes, int n_in,
                              void* d_out, int out_size, void* d_ws, size_t ws_size,
                              hipStream_t stream) {
    const float* x    = (const float*)d_in[0];
    const int*   mask = (const int*)d_in[1];
    float*       out  = (float*)d_out;

    int blocks = TOT_ / 256;     // 49152
    AdaptiveQuadInterp3d_kernel<<<blocks, 256, 0, stream>>>(x, mask, out);
}